// Round 6
// baseline (439.441 us; speedup 1.0000x reference)
//
#include <hip/hip_runtime.h>
#include <hip/hip_bf16.h>
#include <math.h>

#define DIM 2048
#define NH 16
#define HD 128
#define WIN 512

typedef __hip_bfloat16 bf16;
using frag8 = __attribute__((ext_vector_type(8))) short;  // 8 bf16 (4 VGPRs)
using facc4 = __attribute__((ext_vector_type(4))) float;  // 4 fp32 acc

// ---------- conversion helpers ----------
__device__ inline float toF(const bf16 v) { return __bfloat162float(v); }
template <typename T> __device__ inline T fromF(float v);
template <> __device__ inline float fromF<float>(float v) { return v; }
template <> __device__ inline bf16 fromF<bf16>(float v) { return __float2bfloat16(v); }

// fp32 -> bf16 bits, round-to-nearest-even
__device__ inline unsigned bfb(float x) {
    unsigned u = __float_as_uint(x);
    u += 0x7fffu + ((u >> 16) & 1u);
    return u >> 16;
}

// pack 8 fp32 -> 8 bf16 (one uint4)
__device__ inline uint4 pack8(const float* p) {
    const float4 v0 = *(const float4*)p;
    const float4 v1 = *(const float4*)(p + 4);
    uint4 r;
    r.x = bfb(v0.x) | (bfb(v0.y) << 16);
    r.y = bfb(v0.z) | (bfb(v0.w) << 16);
    r.z = bfb(v1.x) | (bfb(v1.y) << 16);
    r.w = bfb(v1.z) | (bfb(v1.w) << 16);
    return r;
}

// ---------- fp32 -> bf16 bulk convert (single source) ----------
__global__ __launch_bounds__(256) void cvt_f32_bf16(const float* __restrict__ src,
                                                    bf16* __restrict__ dst, int n8) {
    const int i = blockIdx.x * 256 + threadIdx.x;
    if (i < n8) ((uint4*)dst)[i] = pack8(src + (size_t)i * 8);
}

// ---------- 4-source weight convert: dst contiguous [Wq|Wk|Wv|Wo], seg = 2^19 uint4 each ----------
#define W8LOG 19  // (DIM*DIM/8) = 524288 = 2^19
__global__ __launch_bounds__(256) void cvt4_f32_bf16(const float* __restrict__ s0,
                                                     const float* __restrict__ s1,
                                                     const float* __restrict__ s2,
                                                     const float* __restrict__ s3,
                                                     bf16* __restrict__ dst) {
    const int i = blockIdx.x * 256 + threadIdx.x;  // i < 4*2^19
    const int seg = i >> W8LOG;
    const int off = i & ((1 << W8LOG) - 1);
    const float* s = (seg == 0) ? s0 : (seg == 1) ? s1 : (seg == 2) ? s2 : s3;
    ((uint4*)dst)[i] = pack8(s + (size_t)off * 8);
}

// ---------- async global->LDS, 16B per lane, wave-uniform LDS base ----------
__device__ inline void gload_lds16(const bf16* g, short* l) {
    __builtin_amdgcn_global_load_lds(
        (const __attribute__((address_space(1))) unsigned int*)g,
        (__attribute__((address_space(3))) unsigned int*)l, 16, 0, 0);
}

// ===================================================================================
// 256x256 8-phase GEMM (m201-style): C[m,n] = sum_k A[m,k]*B[n,k], bf16 in.
// 512 thr = 8 waves (2Mx4N), per-wave 128x64 out, BK=64, 2 K-tiles / iteration.
// LDS 128 KiB double-buffered; staging via global_load_lds w/ pre-swizzled source
// (slot ^= row&7) so ds_read_b128 is conflict-free (R2: SQ_LDS_BANK_CONFLICT = 0);
// counted vmcnt(6) at ph4/ph8 only. MAIN LOOP IS VERIFIED (R2) — DO NOT TOUCH.
// Epilogue fusions (verified R5): RoPE via sincos anchors + exact complex rotation
// (Q/K blocks); V->Vt transpose via LDS scratch, coalesced writes (V blocks).
// ===================================================================================

#define WAIT_LGKM0()                                             \
    do {                                                         \
        asm volatile("s_waitcnt lgkmcnt(0)" ::: "memory");       \
        __builtin_amdgcn_sched_barrier(0);                       \
    } while (0)

#define READ_A(BUF, MI)                                                          \
    do {                                                                         \
        _Pragma("unroll") for (int ii = 0; ii < 4; ++ii)                         \
        _Pragma("unroll") for (int kk = 0; kk < 2; ++kk) {                       \
            const int row_ = wm * 128 + (MI) * 64 + ii * 16 + mr;                \
            const int slot_ = ((kk << 2) + q) ^ (row_ & 7);                      \
            a[ii][kk] = *(const frag8*)&lds[BUF][0][row_][slot_ << 3];           \
        }                                                                        \
    } while (0)

#define READ_B(BUF, NI)                                                          \
    do {                                                                         \
        _Pragma("unroll") for (int jj = 0; jj < 2; ++jj)                         \
        _Pragma("unroll") for (int kk = 0; kk < 2; ++kk) {                       \
            const int row_ = wn * 64 + (NI) * 32 + jj * 16 + mr;                 \
            const int slot_ = ((kk << 2) + q) ^ (row_ & 7);                      \
            b[NI][jj][kk] = *(const frag8*)&lds[BUF][1][row_][slot_ << 3];       \
        }                                                                        \
    } while (0)

#define MFMA_QUAD(MI, NI)                                                        \
    do {                                                                         \
        __builtin_amdgcn_s_setprio(1);                                           \
        _Pragma("unroll") for (int ii = 0; ii < 4; ++ii)                         \
        _Pragma("unroll") for (int jj = 0; jj < 2; ++jj)                         \
        _Pragma("unroll") for (int kk = 0; kk < 2; ++kk)                         \
            acc[(MI) * 4 + ii][(NI) * 2 + jj] =                                  \
                __builtin_amdgcn_mfma_f32_16x16x32_bf16(                         \
                    a[ii][kk], b[NI][jj][kk], acc[(MI) * 4 + ii][(NI) * 2 + jj], \
                    0, 0, 0);                                                    \
        __builtin_amdgcn_s_setprio(0);                                           \
    } while (0)

template <typename TC, bool SPLIT>
__global__ __launch_bounds__(512, 2) void gemm256_8ph(const bf16* __restrict__ A,
                                                      const bf16* __restrict__ B,
                                                      TC* __restrict__ C,
                                                      bf16* __restrict__ Qp,
                                                      bf16* __restrict__ Kp,
                                                      bf16* __restrict__ Vp,
                                                      int M, int N, int K) {
    __shared__ __align__(16) short lds[2][2][256][64];  // [dbuf][A/B][row][k] 128 KiB
    const int tid = threadIdx.x;
    const int lane = tid & 63;
    const int w = tid >> 6;

    // XCD-aware block swizzle (guarded: only when nwg % 8 == 0 -> bijective)
    const int gx = gridDim.x;
    const int nwg = gx * (int)gridDim.y;
    const int lin0 = (int)blockIdx.y * gx + (int)blockIdx.x;
    const int lin = ((nwg & 7) == 0) ? (lin0 & 7) * (nwg >> 3) + (lin0 >> 3) : lin0;
    const int n0 = (lin % gx) * 256;
    const int m0 = (lin / gx) * 256;

    const int wm = w >> 2, wn = w & 3;
    const int q = lane >> 4, mr = lane & 15;
    const int sl = lane & 7, rlo = lane >> 3;
    const int rbA = wm * 128 + wn * 16;            // U0 wave base; U1 = +64
    const int rbB = (w >> 1) * 64 + (w & 1) * 16;  // U2 wave base; U3 = +32

    const int nt = K >> 6;  // K-tiles; requires K % 128 == 0
    const int nIter = nt >> 1;

    facc4 acc[8][4];
#pragma unroll
    for (int i = 0; i < 8; ++i)
#pragma unroll
        for (int j = 0; j < 4; ++j)
#pragma unroll
            for (int r = 0; r < 4; ++r) acc[i][j][r] = 0.f;

    frag8 a[4][2], b[2][2][2];

    // one staging unit = 16 KiB = 2 x global_load_lds(16B) per thread.
    // LDS dest is linear (gload constraint); the XOR swizzle is applied by
    // permuting the per-lane GLOBAL source chunk (slot sl fetches chunk sl^rlo),
    // so LDS[r][sl] = global[r][sl ^ (r&7)] and the read XORs it back.
    auto stage = [&](const bf16* __restrict__ G, int grb, int mat, int buf, int ub, int t) {
        const int kt = t < nt ? t : nt - 1;  // clamp: tail stages read valid mem, never consumed
        const int k0 = kt << 6;
#pragma unroll
        for (int u = 0; u < 2; ++u) {
            const int row0 = ub + u * 8;  // wave-uniform, multiple of 8
            const int row = row0 + rlo;
            gload_lds16(G + (size_t)(grb + row) * K + k0 + ((sl ^ rlo) << 3),
                        (short*)&lds[buf][mat][row0][0]);
        }
    };

    // ---- prologue: tile0 -> buf0 (all 4 units); tile1 -> buf1 (U0,U2,U3) ----
    stage(A, m0, 0, 0, rbA, 0);
    stage(A, m0, 0, 0, rbA + 64, 0);
    stage(B, n0, 1, 0, rbB, 0);
    stage(B, n0, 1, 0, rbB + 32, 0);
    stage(A, m0, 0, 1, rbA, 1);
    stage(B, n0, 1, 1, rbB, 1);
    stage(B, n0, 1, 1, rbB + 32, 1);
    asm volatile("s_waitcnt vmcnt(6)" ::: "memory");  // tile0 fully landed
    __builtin_amdgcn_s_barrier();

    for (int it = 0; it < nIter; ++it) {
        const int t2 = 2 * it + 2;
        // ================ K-tile 2it (buf0) ================
        // PH1: quad (0,0)
        READ_A(0, 0);
        READ_B(0, 0);
        stage(A, m0, 0, 1, rbA + 64, 2 * it + 1);  // U1(2it+1) -> buf1
        __builtin_amdgcn_s_barrier();
        WAIT_LGKM0();
        MFMA_QUAD(0, 0);
        __builtin_amdgcn_s_barrier();
        // PH2: quad (0,1)
        READ_B(0, 1);
        stage(A, m0, 0, 0, rbA, t2);               // U0(t2) -> buf0
        __builtin_amdgcn_s_barrier();
        WAIT_LGKM0();
        MFMA_QUAD(0, 1);
        __builtin_amdgcn_s_barrier();
        // PH3: quad (1,0)
        READ_A(0, 1);
        stage(B, n0, 1, 0, rbB, t2);               // U2(t2) -> buf0
        __builtin_amdgcn_s_barrier();
        WAIT_LGKM0();
        MFMA_QUAD(1, 0);
        __builtin_amdgcn_s_barrier();
        // PH4: quad (1,1) — buffer-switch gate
        stage(B, n0, 1, 0, rbB + 32, t2);          // U3(t2) -> buf0
        __builtin_amdgcn_s_barrier();
        __builtin_amdgcn_sched_barrier(0);
        MFMA_QUAD(1, 1);
        asm volatile("s_waitcnt vmcnt(6)" ::: "memory");  // tile 2it+1 landed
        __builtin_amdgcn_s_barrier();
        // ================ K-tile 2it+1 (buf1) ================
        // PH5: quad (0,0)
        READ_A(1, 0);
        READ_B(1, 0);
        stage(A, m0, 0, 0, rbA + 64, t2);          // U1(t2) -> buf0
        __builtin_amdgcn_s_barrier();
        WAIT_LGKM0();
        MFMA_QUAD(0, 0);
        __builtin_amdgcn_s_barrier();
        // PH6: quad (0,1)
        READ_B(1, 1);
        stage(A, m0, 0, 1, rbA, t2 + 1);           // U0(t2+1) -> buf1
        __builtin_amdgcn_s_barrier();
        WAIT_LGKM0();
        MFMA_QUAD(0, 1);
        __builtin_amdgcn_s_barrier();
        // PH7: quad (1,0)
        READ_A(1, 1);
        stage(B, n0, 1, 1, rbB, t2 + 1);           // U2(t2+1) -> buf1
        __builtin_amdgcn_s_barrier();
        WAIT_LGKM0();
        MFMA_QUAD(1, 0);
        __builtin_amdgcn_s_barrier();
        // PH8: quad (1,1) — buffer-switch gate
        stage(B, n0, 1, 1, rbB + 32, t2 + 1);      // U3(t2+1) -> buf1
        __builtin_amdgcn_s_barrier();
        __builtin_amdgcn_sched_barrier(0);
        MFMA_QUAD(1, 1);
        asm volatile("s_waitcnt vmcnt(6)" ::: "memory");  // tile t2 landed
        __builtin_amdgcn_s_barrier();
    }

    // ---- epilogue ----
    if (SPLIT) {
        if (n0 < 2 * DIM) {
            // Q/K blocks: fused RoPE on fp32 acc, then single bf16 round.
            // col pair partner lives in lane mr^1; even col: v*c - p*s, odd: v*c + p*s.
            // 3 sincosf anchors per jn (base angle, +1-row rotor, +16-row rotor),
            // all 32 rows derived by exact complex rotation (4 mul + 2 add each).
            bf16* dst = (n0 < DIM) ? Qp : Kp;
            const int nb = n0 % DIM;
            const int row0 = m0 + wm * 128 + q * 4;
#pragma unroll
            for (int jn = 0; jn < 4; ++jn) {
                const int col = nb + wn * 64 + jn * 16 + mr;
                const int f = (col & 127) >> 1;  // pair index within head
                const float inv = __expf(-0.14391157f * (float)f);
                const float sgn = (col & 1) ? 1.f : -1.f;
                float cb_, sb_, c1, s1, c16, s16;
                sincosf((float)row0 * inv, &sb_, &cb_);
                sincosf(inv, &s1, &c1);
                sincosf(16.f * inv, &s16, &c16);
#pragma unroll
                for (int im = 0; im < 8; ++im) {
                    float c = cb_, s = sb_;
#pragma unroll
                    for (int r = 0; r < 4; ++r) {
                        const float v = acc[im][jn][r];
                        const float p = __shfl_xor(v, 1, 64);
                        dst[(size_t)(row0 + im * 16 + r) * DIM + col] =
                            fromF<bf16>(v * c + sgn * p * s);
                        const float cn = c * c1 - s * s1;
                        const float sn = s * c1 + c * s1;
                        c = cn; s = sn;
                    }
                    const float cbn = cb_ * c16 - sb_ * s16;
                    const float sbn = sb_ * c16 + cb_ * s16;
                    cb_ = cbn; sb_ = sbn;
                }
            }
        } else {
            // V blocks: transpose via LDS scratch, then coalesced Vt writes.
            // MUST drain in-flight tail global_load_lds first — they land in lds.
            asm volatile("s_waitcnt vmcnt(0)" ::: "memory");
            __builtin_amdgcn_s_barrier();
            short* sc = (short*)lds;         // scratch [128 colL][264 s] = 67584 B
            const int cb = n0 - 2 * DIM;     // head-col base (multiple of 256)
            const int colR = tid >> 2;       // read-phase column 0..127
#pragma unroll
            for (int half = 0; half < 2; ++half) {
                if (half) __builtin_amdgcn_s_barrier();  // reads of half 0 done
                if ((wn >> 1) == half) {
                    // this wave owns cols [half*128 + (wn&1)*64 ... +64)
#pragma unroll
                    for (int im = 0; im < 8; ++im) {
                        const int s = wm * 128 + im * 16 + q * 4;
#pragma unroll
                        for (int jn = 0; jn < 4; ++jn) {
                            const int cl = (wn & 1) * 64 + jn * 16 + mr;
                            uint2 pk;
                            pk.x = bfb(acc[im][jn][0]) | (bfb(acc[im][jn][1]) << 16);
                            pk.y = bfb(acc[im][jn][2]) | (bfb(acc[im][jn][3]) << 16);
                            *(uint2*)&sc[cl * 264 + s] = pk;
                        }
                    }
                }
                __builtin_amdgcn_s_barrier();
                // read back: 8 rounds x 16B/thread; per wave-instruction the 4
                // lanes of a column cover 64B contiguous -> full cache lines.
#pragma unroll
                for (int rr = 0; rr < 8; ++rr) {
                    const int s0 = (tid & 3) * 8 + rr * 32;
                    const uint4 v = *(const uint4*)&sc[colR * 264 + s0];
                    *(uint4*)(Vp + (size_t)(cb + half * 128 + colR) * M + m0 + s0) = v;
                }
            }
        }
    } else {
#pragma unroll
        for (int im = 0; im < 8; ++im)
#pragma unroll
            for (int jn = 0; jn < 4; ++jn) {
                const int col = n0 + wn * 64 + jn * 16 + mr;
#pragma unroll
                for (int r = 0; r < 4; ++r) {
                    const int row = m0 + wm * 128 + im * 16 + q * 4 + r;
                    C[(size_t)row * N + col] = fromF<TC>(acc[im][jn][r]);
                }
            }
    }
}

// ---------- MFMA GEMM (m97 structure), kept for the Wo projection ----------
// (256-tile kernel would give only 128 workgroups there -> half the CUs idle.)
template <typename TC>
__global__ __launch_bounds__(256) void gemm_bt_async(const bf16* __restrict__ A,
                                                     const bf16* __restrict__ B,
                                                     TC* __restrict__ C,
                                                     int M, int N, int K) {
    __shared__ short As[128 * 32];  // row-major [row][k], no padding (global_load_lds constraint)
    __shared__ short Bs[128 * 32];
    const int tid = threadIdx.x;
    const int lane = tid & 63;
    const int w = tid >> 6;
    const int m0 = blockIdx.y * 128;
    const int n0 = blockIdx.x * 128;
    const int wm = (w >> 1) * 64;
    const int wn = (w & 1) * 64;
    const int q = lane >> 4;
    const int mr = lane & 15;

    facc4 acc[4][4];
#pragma unroll
    for (int i = 0; i < 4; ++i)
#pragma unroll
        for (int j = 0; j < 4; ++j)
#pragma unroll
            for (int r = 0; r < 4; ++r) acc[i][j][r] = 0.f;

    for (int k0 = 0; k0 < K; k0 += 32) {
        __syncthreads();
#pragma unroll
        for (int u = 0; u < 2; ++u) {
            const int c = w * 128 + u * 64 + lane;
            const int row = c >> 2, col = (c & 3) * 8;
            gload_lds16(A + (size_t)(m0 + row) * K + k0 + col, As + (w * 128 + u * 64) * 8);
            gload_lds16(B + (size_t)(n0 + row) * K + k0 + col, Bs + (w * 128 + u * 64) * 8);
        }
        __syncthreads();

        frag8 af[4], bfr[4];
#pragma unroll
        for (int i = 0; i < 4; ++i)
            af[i] = *(const frag8*)&As[(wm + 16 * i + mr) * 32 + q * 8];
#pragma unroll
        for (int j = 0; j < 4; ++j)
            bfr[j] = *(const frag8*)&Bs[(wn + 16 * j + mr) * 32 + q * 8];
#pragma unroll
        for (int i = 0; i < 4; ++i)
#pragma unroll
            for (int j = 0; j < 4; ++j)
                acc[i][j] = __builtin_amdgcn_mfma_f32_16x16x32_bf16(af[i], bfr[j], acc[i][j], 0, 0, 0);
    }

#pragma unroll
    for (int i = 0; i < 4; ++i)
#pragma unroll
        for (int j = 0; j < 4; ++j) {
            const int col = n0 + wn + 16 * j + mr;
#pragma unroll
            for (int r = 0; r < 4; ++r) {
                const int row = m0 + wm + 16 * i + q * 4 + r;
                C[(size_t)row * N + col] = fromF<TC>(acc[i][j][r]);
            }
        }
}

// ---------- flash sliding-window attention (reads pre-transposed Vt) ----------
// Block = 64 queries x 1 head, 256 threads (4 waves, wave w owns query rows w*16..w*16+15).
// LDS: Qs[64][136] (reused as Ps[64][72]) | Ks[64][136] | VtL[128][72]  = 53248 B -> 3 blocks/CU.
// R6: T14 async-STAGE split (K/V tile t+1 loaded into 32 staging VGPRs during tile
// t's compute; written to LDS after the loop-top barrier) + removed the softmax->PV
// barrier (Ps rows are written AND read by the same wave; intra-wave lgkmcnt orders)
// + T5 setprio around both MFMA clusters. 3 barriers/tile -> 2, HBM latency hidden.
__global__ __launch_bounds__(256, 3) void flash_swa(const bf16* __restrict__ Q,
                                                    const bf16* __restrict__ K,
                                                    const bf16* __restrict__ Vt,
                                                    bf16* __restrict__ O, int S) {
    __shared__ __align__(16) char lds[53248];
    short* Qs = (short*)lds;               // [64][136]
    short* Ps = (short*)lds;               // [64][72], reuses Qs space
    short* Ks = (short*)(lds + 17408);     // [64][136]
    short* VtL = (short*)(lds + 34816);    // [128][72]  (VtL[d][k])

    const int tid = threadIdx.x;
    const int lane = tid & 63;
    const int w = tid >> 6;
    const int q = lane >> 4;
    const int mr = lane & 15;
    const int i0 = blockIdx.x * 64;
    const int h = blockIdx.y;
    const float scale = 0.08838834764831845f;

#pragma unroll
    for (int u = 0; u < 4; ++u) {
        const int c = tid + 256 * u;
        const int row = c >> 4, col = (c & 15) * 8;
        *(uint4*)&Qs[row * 136 + col] =
            *(const uint4*)(Q + (size_t)(i0 + row) * DIM + h * HD + col);
    }
    __syncthreads();
    frag8 qf[4];
#pragma unroll
    for (int kk = 0; kk < 4; ++kk)
        qf[kk] = *(const frag8*)&Qs[(w * 16 + mr) * 136 + kk * 32 + q * 8];

    float mrow[4], lrow[4];
    facc4 oacc[8];
#pragma unroll
    for (int r = 0; r < 4; ++r) { mrow[r] = -1e30f; lrow[r] = 0.f; }
#pragma unroll
    for (int dt = 0; dt < 8; ++dt)
#pragma unroll
        for (int r = 0; r < 4; ++r) oacc[dt][r] = 0.f;

    const bf16* vtg = Vt + (size_t)h * HD * S;

    // per-thread staging geometry (constant across tiles):
    //   K: row = (tid>>4) + 16u, col = (tid&15)*8   -> Ks[row][col], 16B
    //   V: d   = (tid>>3) + 32u, kc  = (tid&7)*8    -> VtL[d][kc], 16B
    const bf16* kbase = K + (size_t)(tid >> 4) * DIM + h * HD + (tid & 15) * 8;
    const bf16* vbase = vtg + (size_t)(tid >> 3) * S + (tid & 7) * 8;
    short* kdst = &Ks[(tid >> 4) * 136 + (tid & 15) * 8];
    short* vdst = &VtL[(tid >> 3) * 72 + (tid & 7) * 8];

    const int t0 = (i0 >= WIN) ? 0 : (WIN - i0) / 64;
    uint4 kst[4], vst[4];
    {   // prologue: issue tile-t0 loads into staging regs
        const int jb = i0 - WIN + t0 * 64;
#pragma unroll
        for (int u = 0; u < 4; ++u) {
            kst[u] = *(const uint4*)(kbase + (size_t)(jb + 16 * u) * DIM);
            vst[u] = *(const uint4*)(vbase + (size_t)(32 * u) * S + jb);
        }
    }

    for (int t = t0; t < 9; ++t) {
        const int jb = i0 - WIN + t * 64;
        // loop-top barrier: prior tile's LDS reads done AND (via __syncthreads
        // vmcnt drain) staging regs ready.
        __syncthreads();
#pragma unroll
        for (int u = 0; u < 4; ++u) {
            *(uint4*)(kdst + u * 16 * 136) = kst[u];
            *(uint4*)(vdst + u * 32 * 72) = vst[u];
        }
        __syncthreads();  // staged tile visible to all waves

        // issue next tile's loads now; latency hides under QK+softmax+PV (T14)
        if (t < 8) {
            const int jbn = jb + 64;
#pragma unroll
            for (int u = 0; u < 4; ++u) {
                kst[u] = *(const uint4*)(kbase + (size_t)(jbn + 16 * u) * DIM);
                vst[u] = *(const uint4*)(vbase + (size_t)(32 * u) * S + jbn);
            }
        }

        // ---- QK^T: wave computes 16x64 scores ----
        facc4 sacc[4];
#pragma unroll
        for (int nt = 0; nt < 4; ++nt) {
#pragma unroll
            for (int r = 0; r < 4; ++r) sacc[nt][r] = 0.f;
        }
        __builtin_amdgcn_s_setprio(1);
#pragma unroll
        for (int nt = 0; nt < 4; ++nt) {
#pragma unroll
            for (int kk = 0; kk < 4; ++kk) {
                const frag8 kfr = *(const frag8*)&Ks[(nt * 16 + mr) * 136 + kk * 32 + q * 8];
                sacc[nt] = __builtin_amdgcn_mfma_f32_16x16x32_bf16(qf[kk], kfr, sacc[nt], 0, 0, 0);
            }
        }
        __builtin_amdgcn_s_setprio(0);

        float sv[4][4];
        float rmax[4] = {-1e30f, -1e30f, -1e30f, -1e30f};
#pragma unroll
        for (int nt = 0; nt < 4; ++nt) {
            const int j = jb + nt * 16 + mr;
#pragma unroll
            for (int r = 0; r < 4; ++r) {
                const int i = i0 + w * 16 + q * 4 + r;
                const bool valid = (j <= i) && (i - j < WIN);
                sv[nt][r] = valid ? sacc[nt][r] * scale : -1e30f;
                rmax[r] = fmaxf(rmax[r], sv[nt][r]);
            }
        }
#pragma unroll
        for (int msk = 1; msk <= 8; msk <<= 1)
#pragma unroll
            for (int r = 0; r < 4; ++r)
                rmax[r] = fmaxf(rmax[r], __shfl_xor(rmax[r], msk, 64));

        float alpha[4], rsum[4];
#pragma unroll
        for (int r = 0; r < 4; ++r) {
            const float mn = fmaxf(mrow[r], rmax[r]);
            alpha[r] = __expf(mrow[r] - mn);
            mrow[r] = mn;
            rsum[r] = 0.f;
        }
#pragma unroll
        for (int nt = 0; nt < 4; ++nt)
#pragma unroll
            for (int r = 0; r < 4; ++r) {
                const float pv = (sv[nt][r] > -1e29f) ? __expf(sv[nt][r] - mrow[r]) : 0.f;
                rsum[r] += pv;
                Ps[(w * 16 + q * 4 + r) * 72 + nt * 16 + mr] = (short)bfb(pv);
            }
#pragma unroll
        for (int msk = 1; msk <= 8; msk <<= 1)
#pragma unroll
            for (int r = 0; r < 4; ++r)
                rsum[r] += __shfl_xor(rsum[r], msk, 64);
#pragma unroll
        for (int r = 0; r < 4; ++r) lrow[r] = lrow[r] * alpha[r] + rsum[r];
#pragma unroll
        for (int dt = 0; dt < 8; ++dt)
#pragma unroll
            for (int r = 0; r < 4; ++r) oacc[dt][r] *= alpha[r];

        // NO barrier here: Ps rows written above and read below belong to the
        // SAME wave (write rows w*16+q*4+r, read rows w*16+mr); lgkmcnt orders.
        __builtin_amdgcn_s_setprio(1);
#pragma unroll
        for (int ks = 0; ks < 2; ++ks) {
            const frag8 pf = *(const frag8*)&Ps[(w * 16 + mr) * 72 + ks * 32 + q * 8];
#pragma unroll
            for (int dt = 0; dt < 8; ++dt) {
                const frag8 vf = *(const frag8*)&VtL[(dt * 16 + mr) * 72 + ks * 32 + q * 8];
                oacc[dt] = __builtin_amdgcn_mfma_f32_16x16x32_bf16(pf, vf, oacc[dt], 0, 0, 0);
            }
        }
        __builtin_amdgcn_s_setprio(0);
    }

    float inv[4];
#pragma unroll
    for (int r = 0; r < 4; ++r) inv[r] = 1.0f / lrow[r];
#pragma unroll
    for (int dt = 0; dt < 8; ++dt)
#pragma unroll
        for (int r = 0; r < 4; ++r) {
            const int row = i0 + w * 16 + q * 4 + r;
            O[(size_t)row * DIM + h * HD + dt * 16 + mr] = fromF<bf16>(oacc[dt][r] * inv[r]);
        }
}

extern "C" void kernel_launch(void* const* d_in, const int* in_sizes, int n_in,
                              void* d_out, int out_size, void* d_ws, size_t ws_size,
                              hipStream_t stream) {
    const float* x  = (const float*)d_in[0];
    const float* Wq = (const float*)d_in[1];
    const float* Wk = (const float*)d_in[2];
    const float* Wv = (const float*)d_in[3];
    const float* Wo = (const float*)d_in[4];
    float* out = (float*)d_out;

    const int S = in_sizes[0] / DIM;          // 4096
    const size_t elems = (size_t)S * DIM;     // 8.39M
    const size_t wsz = (size_t)DIM * DIM;     // 4.19M

    bf16* Q    = (bf16*)d_ws;
    bf16* K    = Q + elems;
    bf16* V    = K + elems;    // holds Vt[h][d][S] directly (GEMM epilogue writes transposed)
    bf16* Aat  = V + elems;
    bf16* xb   = Aat + elems;  // x(bf16) for QKV GEMM
    bf16* Wcat = xb + elems;   // [4*DIM][DIM]: Wq | Wk | Wv | Wo (contiguous)
    bf16* Wob  = Wcat + 3 * wsz;
    // total ws use: (5*elems + 4*wsz)*2B = 117 MB

    cvt_f32_bf16<<<(int)(elems / 8 / 256), 256, 0, stream>>>(x, xb, (int)(elems / 8));
    cvt4_f32_bf16<<<(int)(4 * wsz / 8 / 256), 256, 0, stream>>>(Wq, Wk, Wv, Wo, Wcat);

    // fused QKV projection + RoPE(Q,K) + V->Vt transpose, 256x256 8-phase kernel
    gemm256_8ph<bf16, true><<<dim3(3 * DIM / 256, S / 256), 512, 0, stream>>>(
        xb, Wcat, (bf16*)nullptr, Q, K, V, S, 3 * DIM, DIM);

    flash_swa<<<dim3(S / 64, NH), 256, 0, stream>>>(Q, K, V, Aat, S);

    // Wo projection: only 128 wg at 256-tile -> keep 128-tile kernel (512 wg, 2/CU)
    gemm_bt_async<float><<<dim3(DIM / 128, S / 128), 256, 0, stream>>>(
        Aat, Wob, out, S, DIM, DIM);
}

// Round 7
// 375.538 us; speedup vs baseline: 1.1702x; 1.1702x over previous
//
#include <hip/hip_runtime.h>
#include <hip/hip_bf16.h>
#include <math.h>

#define DIM 2048
#define NH 16
#define HD 128
#define WIN 512

typedef __hip_bfloat16 bf16;
using frag8 = __attribute__((ext_vector_type(8))) short;  // 8 bf16 (4 VGPRs)
using facc4 = __attribute__((ext_vector_type(4))) float;  // 4 fp32 acc

// ---------- conversion helpers ----------
__device__ inline float toF(const bf16 v) { return __bfloat162float(v); }
template <typename T> __device__ inline T fromF(float v);
template <> __device__ inline float fromF<float>(float v) { return v; }
template <> __device__ inline bf16 fromF<bf16>(float v) { return __float2bfloat16(v); }

// fp32 -> bf16 bits, round-to-nearest-even
__device__ inline unsigned bfb(float x) {
    unsigned u = __float_as_uint(x);
    u += 0x7fffu + ((u >> 16) & 1u);
    return u >> 16;
}

// pack 8 fp32 -> 8 bf16 (one uint4)
__device__ inline uint4 pack8(const float* p) {
    const float4 v0 = *(const float4*)p;
    const float4 v1 = *(const float4*)(p + 4);
    uint4 r;
    r.x = bfb(v0.x) | (bfb(v0.y) << 16);
    r.y = bfb(v0.z) | (bfb(v0.w) << 16);
    r.z = bfb(v1.x) | (bfb(v1.y) << 16);
    r.w = bfb(v1.z) | (bfb(v1.w) << 16);
    return r;
}

// ---------- fp32 -> bf16 bulk convert (single source) ----------
__global__ __launch_bounds__(256) void cvt_f32_bf16(const float* __restrict__ src,
                                                    bf16* __restrict__ dst, int n8) {
    const int i = blockIdx.x * 256 + threadIdx.x;
    if (i < n8) ((uint4*)dst)[i] = pack8(src + (size_t)i * 8);
}

// ---------- 4-source weight convert: dst contiguous [Wq|Wk|Wv|Wo], seg = 2^19 uint4 each ----------
#define W8LOG 19  // (DIM*DIM/8) = 524288 = 2^19
__global__ __launch_bounds__(256) void cvt4_f32_bf16(const float* __restrict__ s0,
                                                     const float* __restrict__ s1,
                                                     const float* __restrict__ s2,
                                                     const float* __restrict__ s3,
                                                     bf16* __restrict__ dst) {
    const int i = blockIdx.x * 256 + threadIdx.x;  // i < 4*2^19
    const int seg = i >> W8LOG;
    const int off = i & ((1 << W8LOG) - 1);
    const float* s = (seg == 0) ? s0 : (seg == 1) ? s1 : (seg == 2) ? s2 : s3;
    ((uint4*)dst)[i] = pack8(s + (size_t)off * 8);
}

// ---------- async global->LDS, 16B per lane, wave-uniform LDS base ----------
__device__ inline void gload_lds16(const bf16* g, short* l) {
    __builtin_amdgcn_global_load_lds(
        (const __attribute__((address_space(1))) unsigned int*)g,
        (__attribute__((address_space(3))) unsigned int*)l, 16, 0, 0);
}

// ===================================================================================
// 256x256 8-phase GEMM (m201-style): C[m,n] = sum_k A[m,k]*B[n,k], bf16 in.
// 512 thr = 8 waves (2Mx4N), per-wave 128x64 out, BK=64, 2 K-tiles / iteration.
// LDS 128 KiB double-buffered; staging via global_load_lds w/ pre-swizzled source
// (slot ^= row&7) so ds_read_b128 is conflict-free (R2: SQ_LDS_BANK_CONFLICT = 0);
// counted vmcnt(6) at ph4/ph8 only. MAIN LOOP IS VERIFIED (R2) — DO NOT TOUCH.
// Epilogue fusions (verified R5): RoPE via sincos anchors + exact complex rotation
// (Q/K blocks); V->Vt transpose via LDS scratch, coalesced writes (V blocks).
// ===================================================================================

#define WAIT_LGKM0()                                             \
    do {                                                         \
        asm volatile("s_waitcnt lgkmcnt(0)" ::: "memory");       \
        __builtin_amdgcn_sched_barrier(0);                       \
    } while (0)

#define READ_A(BUF, MI)                                                          \
    do {                                                                         \
        _Pragma("unroll") for (int ii = 0; ii < 4; ++ii)                         \
        _Pragma("unroll") for (int kk = 0; kk < 2; ++kk) {                       \
            const int row_ = wm * 128 + (MI) * 64 + ii * 16 + mr;                \
            const int slot_ = ((kk << 2) + q) ^ (row_ & 7);                      \
            a[ii][kk] = *(const frag8*)&lds[BUF][0][row_][slot_ << 3];           \
        }                                                                        \
    } while (0)

#define READ_B(BUF, NI)                                                          \
    do {                                                                         \
        _Pragma("unroll") for (int jj = 0; jj < 2; ++jj)                         \
        _Pragma("unroll") for (int kk = 0; kk < 2; ++kk) {                       \
            const int row_ = wn * 64 + (NI) * 32 + jj * 16 + mr;                 \
            const int slot_ = ((kk << 2) + q) ^ (row_ & 7);                      \
            b[NI][jj][kk] = *(const frag8*)&lds[BUF][1][row_][slot_ << 3];       \
        }                                                                        \
    } while (0)

#define MFMA_QUAD(MI, NI)                                                        \
    do {                                                                         \
        __builtin_amdgcn_s_setprio(1);                                           \
        _Pragma("unroll") for (int ii = 0; ii < 4; ++ii)                         \
        _Pragma("unroll") for (int jj = 0; jj < 2; ++jj)                         \
        _Pragma("unroll") for (int kk = 0; kk < 2; ++kk)                         \
            acc[(MI) * 4 + ii][(NI) * 2 + jj] =                                  \
                __builtin_amdgcn_mfma_f32_16x16x32_bf16(                         \
                    a[ii][kk], b[NI][jj][kk], acc[(MI) * 4 + ii][(NI) * 2 + jj], \
                    0, 0, 0);                                                    \
        __builtin_amdgcn_s_setprio(0);                                           \
    } while (0)

template <typename TC, bool SPLIT>
__global__ __launch_bounds__(512, 2) void gemm256_8ph(const bf16* __restrict__ A,
                                                      const bf16* __restrict__ B,
                                                      TC* __restrict__ C,
                                                      bf16* __restrict__ Qp,
                                                      bf16* __restrict__ Kp,
                                                      bf16* __restrict__ Vp,
                                                      int M, int N, int K) {
    __shared__ __align__(16) short lds[2][2][256][64];  // [dbuf][A/B][row][k] 128 KiB
    const int tid = threadIdx.x;
    const int lane = tid & 63;
    const int w = tid >> 6;

    // XCD-aware block swizzle (guarded: only when nwg % 8 == 0 -> bijective)
    const int gx = gridDim.x;
    const int nwg = gx * (int)gridDim.y;
    const int lin0 = (int)blockIdx.y * gx + (int)blockIdx.x;
    const int lin = ((nwg & 7) == 0) ? (lin0 & 7) * (nwg >> 3) + (lin0 >> 3) : lin0;
    const int n0 = (lin % gx) * 256;
    const int m0 = (lin / gx) * 256;

    const int wm = w >> 2, wn = w & 3;
    const int q = lane >> 4, mr = lane & 15;
    const int sl = lane & 7, rlo = lane >> 3;
    const int rbA = wm * 128 + wn * 16;            // U0 wave base; U1 = +64
    const int rbB = (w >> 1) * 64 + (w & 1) * 16;  // U2 wave base; U3 = +32

    const int nt = K >> 6;  // K-tiles; requires K % 128 == 0
    const int nIter = nt >> 1;

    facc4 acc[8][4];
#pragma unroll
    for (int i = 0; i < 8; ++i)
#pragma unroll
        for (int j = 0; j < 4; ++j)
#pragma unroll
            for (int r = 0; r < 4; ++r) acc[i][j][r] = 0.f;

    frag8 a[4][2], b[2][2][2];

    // one staging unit = 16 KiB = 2 x global_load_lds(16B) per thread.
    // LDS dest is linear (gload constraint); the XOR swizzle is applied by
    // permuting the per-lane GLOBAL source chunk (slot sl fetches chunk sl^rlo),
    // so LDS[r][sl] = global[r][sl ^ (r&7)] and the read XORs it back.
    auto stage = [&](const bf16* __restrict__ G, int grb, int mat, int buf, int ub, int t) {
        const int kt = t < nt ? t : nt - 1;  // clamp: tail stages read valid mem, never consumed
        const int k0 = kt << 6;
#pragma unroll
        for (int u = 0; u < 2; ++u) {
            const int row0 = ub + u * 8;  // wave-uniform, multiple of 8
            const int row = row0 + rlo;
            gload_lds16(G + (size_t)(grb + row) * K + k0 + ((sl ^ rlo) << 3),
                        (short*)&lds[buf][mat][row0][0]);
        }
    };

    // ---- prologue: tile0 -> buf0 (all 4 units); tile1 -> buf1 (U0,U2,U3) ----
    stage(A, m0, 0, 0, rbA, 0);
    stage(A, m0, 0, 0, rbA + 64, 0);
    stage(B, n0, 1, 0, rbB, 0);
    stage(B, n0, 1, 0, rbB + 32, 0);
    stage(A, m0, 0, 1, rbA, 1);
    stage(B, n0, 1, 1, rbB, 1);
    stage(B, n0, 1, 1, rbB + 32, 1);
    asm volatile("s_waitcnt vmcnt(6)" ::: "memory");  // tile0 fully landed
    __builtin_amdgcn_s_barrier();

    for (int it = 0; it < nIter; ++it) {
        const int t2 = 2 * it + 2;
        // ================ K-tile 2it (buf0) ================
        // PH1: quad (0,0)
        READ_A(0, 0);
        READ_B(0, 0);
        stage(A, m0, 0, 1, rbA + 64, 2 * it + 1);  // U1(2it+1) -> buf1
        __builtin_amdgcn_s_barrier();
        WAIT_LGKM0();
        MFMA_QUAD(0, 0);
        __builtin_amdgcn_s_barrier();
        // PH2: quad (0,1)
        READ_B(0, 1);
        stage(A, m0, 0, 0, rbA, t2);               // U0(t2) -> buf0
        __builtin_amdgcn_s_barrier();
        WAIT_LGKM0();
        MFMA_QUAD(0, 1);
        __builtin_amdgcn_s_barrier();
        // PH3: quad (1,0)
        READ_A(0, 1);
        stage(B, n0, 1, 0, rbB, t2);               // U2(t2) -> buf0
        __builtin_amdgcn_s_barrier();
        WAIT_LGKM0();
        MFMA_QUAD(1, 0);
        __builtin_amdgcn_s_barrier();
        // PH4: quad (1,1) — buffer-switch gate
        stage(B, n0, 1, 0, rbB + 32, t2);          // U3(t2) -> buf0
        __builtin_amdgcn_s_barrier();
        __builtin_amdgcn_sched_barrier(0);
        MFMA_QUAD(1, 1);
        asm volatile("s_waitcnt vmcnt(6)" ::: "memory");  // tile 2it+1 landed
        __builtin_amdgcn_s_barrier();
        // ================ K-tile 2it+1 (buf1) ================
        // PH5: quad (0,0)
        READ_A(1, 0);
        READ_B(1, 0);
        stage(A, m0, 0, 0, rbA + 64, t2);          // U1(t2) -> buf0
        __builtin_amdgcn_s_barrier();
        WAIT_LGKM0();
        MFMA_QUAD(0, 0);
        __builtin_amdgcn_s_barrier();
        // PH6: quad (0,1)
        READ_B(1, 1);
        stage(A, m0, 0, 1, rbA, t2 + 1);           // U0(t2+1) -> buf1
        __builtin_amdgcn_s_barrier();
        WAIT_LGKM0();
        MFMA_QUAD(0, 1);
        __builtin_amdgcn_s_barrier();
        // PH7: quad (1,0)
        READ_A(1, 1);
        stage(B, n0, 1, 1, rbB, t2 + 1);           // U2(t2+1) -> buf1
        __builtin_amdgcn_s_barrier();
        WAIT_LGKM0();
        MFMA_QUAD(1, 0);
        __builtin_amdgcn_s_barrier();
        // PH8: quad (1,1) — buffer-switch gate
        stage(B, n0, 1, 1, rbB + 32, t2 + 1);      // U3(t2+1) -> buf1
        __builtin_amdgcn_s_barrier();
        __builtin_amdgcn_sched_barrier(0);
        MFMA_QUAD(1, 1);
        asm volatile("s_waitcnt vmcnt(6)" ::: "memory");  // tile t2 landed
        __builtin_amdgcn_s_barrier();
    }

    // ---- epilogue ----
    if (SPLIT) {
        if (n0 < 2 * DIM) {
            // Q/K blocks: fused RoPE on fp32 acc, then single bf16 round.
            // col pair partner lives in lane mr^1; even col: v*c - p*s, odd: v*c + p*s.
            // 3 sincosf anchors per jn (base angle, +1-row rotor, +16-row rotor),
            // all 32 rows derived by exact complex rotation (4 mul + 2 add each).
            bf16* dst = (n0 < DIM) ? Qp : Kp;
            const int nb = n0 % DIM;
            const int row0 = m0 + wm * 128 + q * 4;
#pragma unroll
            for (int jn = 0; jn < 4; ++jn) {
                const int col = nb + wn * 64 + jn * 16 + mr;
                const int f = (col & 127) >> 1;  // pair index within head
                const float inv = __expf(-0.14391157f * (float)f);
                const float sgn = (col & 1) ? 1.f : -1.f;
                float cb_, sb_, c1, s1, c16, s16;
                sincosf((float)row0 * inv, &sb_, &cb_);
                sincosf(inv, &s1, &c1);
                sincosf(16.f * inv, &s16, &c16);
#pragma unroll
                for (int im = 0; im < 8; ++im) {
                    float c = cb_, s = sb_;
#pragma unroll
                    for (int r = 0; r < 4; ++r) {
                        const float v = acc[im][jn][r];
                        const float p = __shfl_xor(v, 1, 64);
                        dst[(size_t)(row0 + im * 16 + r) * DIM + col] =
                            fromF<bf16>(v * c + sgn * p * s);
                        const float cn = c * c1 - s * s1;
                        const float sn = s * c1 + c * s1;
                        c = cn; s = sn;
                    }
                    const float cbn = cb_ * c16 - sb_ * s16;
                    const float sbn = sb_ * c16 + cb_ * s16;
                    cb_ = cbn; sb_ = sbn;
                }
            }
        } else {
            // V blocks: transpose via LDS scratch, then coalesced Vt writes.
            // MUST drain in-flight tail global_load_lds first — they land in lds.
            asm volatile("s_waitcnt vmcnt(0)" ::: "memory");
            __builtin_amdgcn_s_barrier();
            short* sc = (short*)lds;         // scratch [128 colL][264 s] = 67584 B
            const int cb = n0 - 2 * DIM;     // head-col base (multiple of 256)
            const int colR = tid >> 2;       // read-phase column 0..127
#pragma unroll
            for (int half = 0; half < 2; ++half) {
                if (half) __builtin_amdgcn_s_barrier();  // reads of half 0 done
                if ((wn >> 1) == half) {
                    // this wave owns cols [half*128 + (wn&1)*64 ... +64)
#pragma unroll
                    for (int im = 0; im < 8; ++im) {
                        const int s = wm * 128 + im * 16 + q * 4;
#pragma unroll
                        for (int jn = 0; jn < 4; ++jn) {
                            const int cl = (wn & 1) * 64 + jn * 16 + mr;
                            uint2 pk;
                            pk.x = bfb(acc[im][jn][0]) | (bfb(acc[im][jn][1]) << 16);
                            pk.y = bfb(acc[im][jn][2]) | (bfb(acc[im][jn][3]) << 16);
                            *(uint2*)&sc[cl * 264 + s] = pk;
                        }
                    }
                }
                __builtin_amdgcn_s_barrier();
                // read back: 8 rounds x 16B/thread; per wave-instruction the 4
                // lanes of a column cover 64B contiguous -> full cache lines.
#pragma unroll
                for (int rr = 0; rr < 8; ++rr) {
                    const int s0 = (tid & 3) * 8 + rr * 32;
                    const uint4 v = *(const uint4*)&sc[colR * 264 + s0];
                    *(uint4*)(Vp + (size_t)(cb + half * 128 + colR) * M + m0 + s0) = v;
                }
            }
        }
    } else {
#pragma unroll
        for (int im = 0; im < 8; ++im)
#pragma unroll
            for (int jn = 0; jn < 4; ++jn) {
                const int col = n0 + wn * 64 + jn * 16 + mr;
#pragma unroll
                for (int r = 0; r < 4; ++r) {
                    const int row = m0 + wm * 128 + im * 16 + q * 4 + r;
                    C[(size_t)row * N + col] = fromF<TC>(acc[im][jn][r]);
                }
            }
    }
}

// ---------- MFMA GEMM (m97 structure), kept for the Wo projection ----------
// (256-tile kernel would give only 128 workgroups there -> half the CUs idle.)
template <typename TC>
__global__ __launch_bounds__(256) void gemm_bt_async(const bf16* __restrict__ A,
                                                     const bf16* __restrict__ B,
                                                     TC* __restrict__ C,
                                                     int M, int N, int K) {
    __shared__ short As[128 * 32];  // row-major [row][k], no padding (global_load_lds constraint)
    __shared__ short Bs[128 * 32];
    const int tid = threadIdx.x;
    const int lane = tid & 63;
    const int w = tid >> 6;
    const int m0 = blockIdx.y * 128;
    const int n0 = blockIdx.x * 128;
    const int wm = (w >> 1) * 64;
    const int wn = (w & 1) * 64;
    const int q = lane >> 4;
    const int mr = lane & 15;

    facc4 acc[4][4];
#pragma unroll
    for (int i = 0; i < 4; ++i)
#pragma unroll
        for (int j = 0; j < 4; ++j)
#pragma unroll
            for (int r = 0; r < 4; ++r) acc[i][j][r] = 0.f;

    for (int k0 = 0; k0 < K; k0 += 32) {
        __syncthreads();
#pragma unroll
        for (int u = 0; u < 2; ++u) {
            const int c = w * 128 + u * 64 + lane;
            const int row = c >> 2, col = (c & 3) * 8;
            gload_lds16(A + (size_t)(m0 + row) * K + k0 + col, As + (w * 128 + u * 64) * 8);
            gload_lds16(B + (size_t)(n0 + row) * K + k0 + col, Bs + (w * 128 + u * 64) * 8);
        }
        __syncthreads();

        frag8 af[4], bfr[4];
#pragma unroll
        for (int i = 0; i < 4; ++i)
            af[i] = *(const frag8*)&As[(wm + 16 * i + mr) * 32 + q * 8];
#pragma unroll
        for (int j = 0; j < 4; ++j)
            bfr[j] = *(const frag8*)&Bs[(wn + 16 * j + mr) * 32 + q * 8];
#pragma unroll
        for (int i = 0; i < 4; ++i)
#pragma unroll
            for (int j = 0; j < 4; ++j)
                acc[i][j] = __builtin_amdgcn_mfma_f32_16x16x32_bf16(af[i], bfr[j], acc[i][j], 0, 0, 0);
    }

#pragma unroll
    for (int i = 0; i < 4; ++i)
#pragma unroll
        for (int j = 0; j < 4; ++j) {
            const int col = n0 + wn + 16 * j + mr;
#pragma unroll
            for (int r = 0; r < 4; ++r) {
                const int row = m0 + wm + 16 * i + q * 4 + r;
                C[(size_t)row * N + col] = fromF<TC>(acc[i][j][r]);
            }
        }
}

// ---------- flash sliding-window attention (reads pre-transposed Vt) ----------
// R7: global_load_lds staging + double-buffered K/V + counted vmcnt(8) (T3/T4).
// Block = 64 queries x 1 head, 256 threads (4 waves). Q held in registers (no LDS).
// LDS: Kd[2][64][128] (32KB) | Vd[2][128][64] (32KB) | Ps[64][72] (9KB) = 74752 B
//   -> 2 blocks/CU, launch_bounds(256,2) => VGPR cap 256 (no spill; R6's 32-VGPR
//      register prefetch under cap 170 spilled and cost +60us).
// XOR swizzle (slot ^= row&7, 16B units) applied via pre-swizzled per-lane GLOBAL
// source (rule #21) since gload_lds writes linearly; reads XOR the same involution.
// Loop: [vmcnt(8)+barrier] QK -> softmax -> PV (same-wave Ps, no barrier)
//       [barrier] issue tile t+2 into freed buffer. Tail issues clamped; vmcnt(0)
//       drains before epilogue (dangling DMA past endpgm could hit foreign LDS).
__global__ __launch_bounds__(256, 2) void flash_swa(const bf16* __restrict__ Q,
                                                    const bf16* __restrict__ K,
                                                    const bf16* __restrict__ Vt,
                                                    bf16* __restrict__ O, int S) {
    __shared__ __align__(16) char lds[74752];
    short* Ksl = (short*)lds;            // [2][64][128]
    short* Vtl = (short*)(lds + 32768);  // [2][128][64]
    short* Ps  = (short*)(lds + 65536);  // [64][72]

    const int tid = threadIdx.x;
    const int lane = tid & 63;
    const int w = tid >> 6;
    const int q = lane >> 4;
    const int mr = lane & 15;
    // XCD-chunked swizzle: 8 consecutive row-blocks (heavily overlapping KV
    // windows) land on one XCD's L2. gridDim.x=64 => lin%8 == bx%8 == XCD.
    const int bx = blockIdx.x;
    const int i0 = (((bx & 7) << 3) | (bx >> 3)) * 64;
    const int h = blockIdx.y;
    const float scale = 0.08838834764831845f;
    const int sw = mr & 7;  // read-side swizzle factor (row&7 == mr&7, rows 16-strided)

    // ---- Q direct to registers (frees 17KB LDS) ----
    frag8 qf[4];
    const bf16* qptr = Q + (size_t)(i0 + w * 16 + mr) * DIM + h * HD + q * 8;
#pragma unroll
    for (int kk = 0; kk < 4; ++kk) qf[kk] = *(const frag8*)(qptr + kk * 32);

    const bf16* vtg = Vt + (size_t)h * HD * S;

    // per-lane staging offsets (within-tile), u = 0..3:
    //   K rows: w*16 + 4u + (lane>>4); chunk (lane&15), src chunk ^= row&7
    //   V rows: w*32 + 8u + (lane>>3); chunk (lane&7),  src chunk ^= row&7
    int koff[4], voff[4];
#pragma unroll
    for (int u = 0; u < 4; ++u) {
        const int krow = w * 16 + 4 * u + (lane >> 4);
        const int kch = (lane & 15) ^ (krow & 7);
        koff[u] = krow * DIM + h * HD + kch * 8;
        const int vrow = w * 32 + 8 * u + (lane >> 3);
        const int vch = (lane & 7) ^ (vrow & 7);
        voff[u] = vrow * S + vch * 8;
    }

    auto issue = [&](int t, int buf) {  // 8 gload_lds16 per thread (4 K + 4 V)
        int jb = i0 - WIN + t * 64;
        if (jb > S - 64) jb = S - 64;  // clamp: tail reads valid mem, never consumed
        const bf16* kb = K + (size_t)jb * DIM;
        const bf16* vb = vtg + jb;
#pragma unroll
        for (int u = 0; u < 4; ++u)
            gload_lds16(kb + koff[u], Ksl + buf * 8192 + (w * 16 + 4 * u) * 128);
#pragma unroll
        for (int u = 0; u < 4; ++u)
            gload_lds16(vb + voff[u], Vtl + buf * 8192 + (w * 32 + 8 * u) * 64);
    };

    float mrow[4], lrow[4];
    facc4 oacc[8];
#pragma unroll
    for (int r = 0; r < 4; ++r) { mrow[r] = -1e30f; lrow[r] = 0.f; }
#pragma unroll
    for (int dt = 0; dt < 8; ++dt)
#pragma unroll
        for (int r = 0; r < 4; ++r) oacc[dt][r] = 0.f;

    const int t0 = (i0 >= WIN) ? 0 : (WIN - i0) / 64;
    issue(t0, 0);
    issue(t0 + 1, 1);
    int p = 0;

    for (int t = t0; t < 9; ++t) {
        const int jb = i0 - WIN + t * 64;
        // tile t landed (its 8 ops are the oldest; tile t+1's 8 stay in flight)
        asm volatile("s_waitcnt vmcnt(8)" ::: "memory");
        __builtin_amdgcn_s_barrier();
        __builtin_amdgcn_sched_barrier(0);

        // ---- QK^T: wave computes 16x64 scores ----
        facc4 sacc[4];
#pragma unroll
        for (int nt = 0; nt < 4; ++nt)
#pragma unroll
            for (int r = 0; r < 4; ++r) sacc[nt][r] = 0.f;
        __builtin_amdgcn_s_setprio(1);
#pragma unroll
        for (int nt = 0; nt < 4; ++nt) {
#pragma unroll
            for (int kk = 0; kk < 4; ++kk) {
                const frag8 kfr = *(const frag8*)&Ksl[p * 8192 + (nt * 16 + mr) * 128 +
                                                      (((kk * 4 + q) ^ sw) << 3)];
                sacc[nt] = __builtin_amdgcn_mfma_f32_16x16x32_bf16(qf[kk], kfr, sacc[nt], 0, 0, 0);
            }
        }
        __builtin_amdgcn_s_setprio(0);

        float sv[4][4];
        float rmax[4] = {-1e30f, -1e30f, -1e30f, -1e30f};
#pragma unroll
        for (int nt = 0; nt < 4; ++nt) {
            const int j = jb + nt * 16 + mr;
#pragma unroll
            for (int r = 0; r < 4; ++r) {
                const int i = i0 + w * 16 + q * 4 + r;
                const bool valid = (j <= i) && (i - j < WIN);
                sv[nt][r] = valid ? sacc[nt][r] * scale : -1e30f;
                rmax[r] = fmaxf(rmax[r], sv[nt][r]);
            }
        }
#pragma unroll
        for (int msk = 1; msk <= 8; msk <<= 1)
#pragma unroll
            for (int r = 0; r < 4; ++r)
                rmax[r] = fmaxf(rmax[r], __shfl_xor(rmax[r], msk, 64));

        float alpha[4], rsum[4];
#pragma unroll
        for (int r = 0; r < 4; ++r) {
            const float mn = fmaxf(mrow[r], rmax[r]);
            alpha[r] = __expf(mrow[r] - mn);
            mrow[r] = mn;
            rsum[r] = 0.f;
        }
#pragma unroll
        for (int nt = 0; nt < 4; ++nt)
#pragma unroll
            for (int r = 0; r < 4; ++r) {
                const float pv = (sv[nt][r] > -1e29f) ? __expf(sv[nt][r] - mrow[r]) : 0.f;
                rsum[r] += pv;
                Ps[(w * 16 + q * 4 + r) * 72 + nt * 16 + mr] = (short)bfb(pv);
            }
#pragma unroll
        for (int msk = 1; msk <= 8; msk <<= 1)
#pragma unroll
            for (int r = 0; r < 4; ++r)
                rsum[r] += __shfl_xor(rsum[r], msk, 64);
#pragma unroll
        for (int r = 0; r < 4; ++r) lrow[r] = lrow[r] * alpha[r] + rsum[r];
#pragma unroll
        for (int dt = 0; dt < 8; ++dt)
#pragma unroll
            for (int r = 0; r < 4; ++r) oacc[dt][r] *= alpha[r];

        // no barrier: Ps rows written above and read below belong to the SAME
        // wave (write rows w*16+q*4+r, read rows w*16+mr); lgkmcnt orders.
        __builtin_amdgcn_s_setprio(1);
#pragma unroll
        for (int ks = 0; ks < 2; ++ks) {
            const frag8 pf = *(const frag8*)&Ps[(w * 16 + mr) * 72 + ks * 32 + q * 8];
#pragma unroll
            for (int dt = 0; dt < 8; ++dt) {
                const frag8 vf = *(const frag8*)&Vtl[p * 8192 + (dt * 16 + mr) * 64 +
                                                     (((ks * 4 + q) ^ sw) << 3)];
                oacc[dt] = __builtin_amdgcn_mfma_f32_16x16x32_bf16(pf, vf, oacc[dt], 0, 0, 0);
            }
        }
        __builtin_amdgcn_s_setprio(0);

        __builtin_amdgcn_s_barrier();        // all waves done reading buf p
        __builtin_amdgcn_sched_barrier(0);
        issue(t + 2, p);                     // refill freed buffer (clamped at tail)
        p ^= 1;
    }
    asm volatile("s_waitcnt vmcnt(0)" ::: "memory");  // drain clamp-issued tail DMAs

    float inv[4];
#pragma unroll
    for (int r = 0; r < 4; ++r) inv[r] = 1.0f / lrow[r];
#pragma unroll
    for (int dt = 0; dt < 8; ++dt)
#pragma unroll
        for (int r = 0; r < 4; ++r) {
            const int row = i0 + w * 16 + q * 4 + r;
            O[(size_t)row * DIM + h * HD + dt * 16 + mr] = fromF<bf16>(oacc[dt][r] * inv[r]);
        }
}

extern "C" void kernel_launch(void* const* d_in, const int* in_sizes, int n_in,
                              void* d_out, int out_size, void* d_ws, size_t ws_size,
                              hipStream_t stream) {
    const float* x  = (const float*)d_in[0];
    const float* Wq = (const float*)d_in[1];
    const float* Wk = (const float*)d_in[2];
    const float* Wv = (const float*)d_in[3];
    const float* Wo = (const float*)d_in[4];
    float* out = (float*)d_out;

    const int S = in_sizes[0] / DIM;          // 4096
    const size_t elems = (size_t)S * DIM;     // 8.39M
    const size_t wsz = (size_t)DIM * DIM;     // 4.19M

    bf16* Q    = (bf16*)d_ws;
    bf16* K    = Q + elems;
    bf16* V    = K + elems;    // holds Vt[h][d][S] directly (GEMM epilogue writes transposed)
    bf16* Aat  = V + elems;
    bf16* xb   = Aat + elems;  // x(bf16) for QKV GEMM
    bf16* Wcat = xb + elems;   // [4*DIM][DIM]: Wq | Wk | Wv | Wo (contiguous)
    bf16* Wob  = Wcat + 3 * wsz;
    // total ws use: (5*elems + 4*wsz)*2B = 117 MB

    cvt_f32_bf16<<<(int)(elems / 8 / 256), 256, 0, stream>>>(x, xb, (int)(elems / 8));
    cvt4_f32_bf16<<<(int)(4 * wsz / 8 / 256), 256, 0, stream>>>(Wq, Wk, Wv, Wo, Wcat);

    // fused QKV projection + RoPE(Q,K) + V->Vt transpose, 256x256 8-phase kernel
    gemm256_8ph<bf16, true><<<dim3(3 * DIM / 256, S / 256), 512, 0, stream>>>(
        xb, Wcat, (bf16*)nullptr, Q, K, V, S, 3 * DIM, DIM);

    flash_swa<<<dim3(S / 64, NH), 256, 0, stream>>>(Q, K, V, Aat, S);

    // Wo projection: only 128 wg at 256-tile -> keep 128-tile kernel (512 wg, 2/CU)
    gemm_bt_async<float><<<dim3(DIM / 128, S / 128), 256, 0, stream>>>(
        Aat, Wob, out, S, DIM, DIM);
}